// Round 5
// baseline (161.308 us; speedup 1.0000x reference)
//
#include <hip/hip_runtime.h>
#include <math.h>

// Both clouds: 16384 x float2, coords ~ N(0,1).
#define NPTS 16384
#define G    64                 // grid is G x G
#define NB   (G * G)            // 4096 bins
#define CAP  128                // points per bin capacity (central bin E~64)
#define OCAP 2048               // overflow list capacity
#define BV   5.0f               // grid covers [-BV, BV]^2 (clamped outside)
#define H    (2.0f * BV / G)    // 0.15625 cell width
#define INVH (1.0f / H)

// ws layout:
//   [0, 32768)          cnt[2][NB]   uint  (bin counters / final counts)
//   [32768, 32776)      ovf_cnt[2]   uint
//   [65536, +8 MB)      binned[2][NB][CAP] float2  (cell-sorted points)
//   [65536+8MB, +32KB)  ovf[2][OCAP] float2

__global__ __launch_bounds__(256) void k_zero(unsigned int* __restrict__ cnt,
                                              float* __restrict__ out) {
    int i = blockIdx.x * 256 + threadIdx.x;
    if (i < 2 * NB + 2) cnt[i] = 0u;   // cnt[2][NB] + ovf_cnt[2] are contiguous
    if (i == 0) out[0] = 0.0f;
}

__global__ __launch_bounds__(256) void k_scatter(
        const float2* __restrict__ pc, const float2* __restrict__ ref,
        unsigned int* __restrict__ cnt, unsigned int* __restrict__ ovf_cnt,
        float2* __restrict__ binned, float2* __restrict__ ovf) {
    int t  = blockIdx.x * 256 + threadIdx.x;   // 0..32767
    int cl = t >> 14;                          // cloud: 0=pc, 1=ref
    int i  = t & (NPTS - 1);
    float2 p = (cl ? ref : pc)[i];
    int bx = (int)floorf((p.x + BV) * INVH); bx = min(max(bx, 0), G - 1);
    int by = (int)floorf((p.y + BV) * INVH); by = min(max(by, 0), G - 1);
    int b = by * G + bx;
    unsigned idx = atomicAdd(&cnt[cl * NB + b], 1u);
    if (idx < CAP) {
        binned[(cl * NB + b) * CAP + idx] = p;
    } else {
        unsigned oi = atomicAdd(&ovf_cnt[cl], 1u);
        if (oi < OCAP) ovf[cl * OCAP + oi] = p;
    }
}

// One wave per (dir, cell): lanes take the cell's (cell-sorted) queries, ring-search
// the other cloud's grid. Wave-uniform trip counts; stop after ring r iff
// all lanes have best_d^2 <= (r*H)^2 (unprocessed cells are >= r*H away).
__global__ __launch_bounds__(256) void k_query(
        const float2* __restrict__ pc, const float2* __restrict__ ref,
        const unsigned int* __restrict__ cnt, const unsigned int* __restrict__ ovf_cnt,
        const float2* __restrict__ binned, const float2* __restrict__ ovf,
        float* __restrict__ out) {
    int d    = blockIdx.y;          // query cloud
    int td   = 1 - d;               // target cloud
    int w    = blockIdx.x * 4 + (threadIdx.x >> 6);
    int lane = threadIdx.x & 63;
    float sum = 0.0f;

    if (w < NB) {
        int c  = w;
        int cx = c & (G - 1), cy = c >> 6;
        const unsigned int* tcnt = cnt + td * NB;
        const float2* tbin = binned + (size_t)td * NB * CAP;
        int nq = (int)min(cnt[d * NB + c], (unsigned)CAP);
        unsigned novf = min(ovf_cnt[td], (unsigned)OCAP);

        for (int base = 0; base < nq; base += 64) {
            bool valid = (base + lane) < nq;
            float2 q = valid ? binned[((size_t)d * NB + c) * CAP + base + lane]
                             : make_float2(0.0f, 0.0f);
            float best = valid ? INFINITY : 0.0f;  // invalid lanes never block __all

            // Overflow targets (normally zero) — scanned unconditionally: exact.
            for (unsigned j = 0; j < novf; ++j) {
                float2 tp = ovf[td * OCAP + j];
                float ddx = q.x - tp.x, ddy = q.y - tp.y;
                best = fminf(best, fmaf(ddx, ddx, ddy * ddy));
            }

            auto scan_cell = [&](int x, int y) {
                if ((unsigned)x < G && (unsigned)y < G) {
                    int t  = y * G + x;
                    int tn = (int)min(tcnt[t], (unsigned)CAP);
                    const float2* tp = tbin + (size_t)t * CAP;
                    for (int j = 0; j < tn; ++j) {
                        float2 pt = tp[j];
                        float ddx = q.x - pt.x, ddy = q.y - pt.y;
                        best = fminf(best, fmaf(ddx, ddx, ddy * ddy));
                    }
                }
            };

            for (int r = 0; r < G; ++r) {
                if (r == 0) {
                    scan_cell(cx, cy);
                } else {
                    for (int dx = -r; dx <= r; ++dx) {
                        scan_cell(cx + dx, cy - r);
                        scan_cell(cx + dx, cy + r);
                    }
                    for (int dy = -r + 1; dy <= r - 1; ++dy) {
                        scan_cell(cx - r, cy + dy);
                        scan_cell(cx + r, cy + dy);
                    }
                }
                float bound = (float)r * H;
                if (__all(best <= bound * bound)) break;
            }
            if (valid) sum += sqrtf(best);
        }
    } else if (w == NB) {
        // Overflow queries (normally none): exact brute force vs raw targets.
        unsigned n = min(ovf_cnt[d], (unsigned)OCAP);
        const float2* tgt = d ? pc : ref;
        for (unsigned i = lane; i < n; i += 64) {
            float2 q = ovf[d * OCAP + i];
            float best = INFINITY;
            for (int j = 0; j < NPTS; ++j) {
                float2 tp = tgt[j];
                float ddx = q.x - tp.x, ddy = q.y - tp.y;
                best = fminf(best, fmaf(ddx, ddx, ddy * ddy));
            }
            sum += sqrtf(best);
        }
    }

    // Wave reduction + one atomic per wave.
#pragma unroll
    for (int off = 32; off > 0; off >>= 1)
        sum += __shfl_down(sum, off, 64);
    if (lane == 0 && sum != 0.0f)
        atomicAdd(out, sum);
}

extern "C" void kernel_launch(void* const* d_in, const int* in_sizes, int n_in,
                              void* d_out, int out_size, void* d_ws, size_t ws_size,
                              hipStream_t stream) {
    const float2* pc  = (const float2*)d_in[0];  // img_render_points (128*128*2 f32)
    const float2* ref = (const float2*)d_in[1];  // ref contour (16384*2 f32)
    float* out = (float*)d_out;

    char* w = (char*)d_ws;
    unsigned int* cnt     = (unsigned int*)(w);               // [2][NB]
    unsigned int* ovf_cnt = (unsigned int*)(w + 32768);       // [2]
    float2*       binned  = (float2*)(w + 65536);             // [2][NB][CAP]
    float2*       ovf     = (float2*)(w + 65536 + (size_t)2 * NB * CAP * sizeof(float2));

    k_zero<<<(2 * NB + 2 + 255) / 256, 256, 0, stream>>>(cnt, out);
    k_scatter<<<(2 * NPTS) / 256, 256, 0, stream>>>(pc, ref, cnt, ovf_cnt, binned, ovf);
    // waves: NB cells + 1 overflow wave per dir -> 1025 blocks of 4 waves, y = dir
    k_query<<<dim3(1025, 2), 256, 0, stream>>>(pc, ref, cnt, ovf_cnt, binned, ovf, out);
}

// Round 6
// 121.386 us; speedup vs baseline: 1.3289x; 1.3289x over previous
//
#include <hip/hip_runtime.h>
#include <math.h>

// Both clouds: 16384 x float2, coords ~ N(0,1).
#define NPTS 16384
#define G    64                 // grid is G x G
#define NB   (G * G)            // 4096 bins
#define CAP  128                // real points per bin capacity (central bin E~64)
#define CAPP (CAP + 4)          // + 4 sentinel slots for over-read-safe float4 scans
#define OCAP 2048               // overflow list capacity
#define BV   5.0f               // grid covers [-BV, BV]^2 (clamped outside)
#define H    (2.0f * BV / G)    // 0.15625 cell width
#define INVH (1.0f / H)

// ws layout:
//   [0, 32768)        cnt[2][NB] uint
//   [32768, 32776)    ovf_cnt[2] uint
//   [65536, +8.3 MB)  binned[2][NB][CAPP] float2 (cell-sorted, sentinel-padded)
//   then              ovf[2][OCAP] float2

__global__ __launch_bounds__(256) void k_zero(unsigned int* __restrict__ cnt,
                                              float* __restrict__ out) {
    int i = blockIdx.x * 256 + threadIdx.x;
    if (i < 2 * NB + 2) cnt[i] = 0u;   // cnt[2][NB] + ovf_cnt[2] contiguous
    if (i == 0) out[0] = 0.0f;
}

__global__ __launch_bounds__(256) void k_scatter(
        const float2* __restrict__ pc, const float2* __restrict__ ref,
        unsigned int* __restrict__ cnt, unsigned int* __restrict__ ovf_cnt,
        float2* __restrict__ binned, float2* __restrict__ ovf) {
    int t  = blockIdx.x * 256 + threadIdx.x;   // 0..32767
    int cl = t >> 14;                          // cloud: 0=pc, 1=ref
    int i  = t & (NPTS - 1);
    float2 p = (cl ? ref : pc)[i];
    int bx = (int)floorf((p.x + BV) * INVH); bx = min(max(bx, 0), G - 1);
    int by = (int)floorf((p.y + BV) * INVH); by = min(max(by, 0), G - 1);
    int b = cl * NB + by * G + bx;
    unsigned idx = atomicAdd(&cnt[b], 1u);
    if (idx < CAP) {
        binned[(size_t)b * CAPP + idx] = p;
    } else {
        unsigned oi = atomicAdd(&ovf_cnt[cl], 1u);
        if (oi < OCAP) ovf[cl * OCAP + oi] = p;
    }
}

// Append 4 sentinel points after each bin's real points so scans can read
// rounded-up float4 chunks without touching poison.
__global__ __launch_bounds__(256) void k_pad(
        const unsigned int* __restrict__ cnt, float2* __restrict__ binned) {
    int b = blockIdx.x * 256 + threadIdx.x;    // 0..8191
    if (b < 2 * NB) {
        unsigned n = min(cnt[b], (unsigned)CAP);
        float2* p = binned + (size_t)b * CAPP + n;
#pragma unroll
        for (int k = 0; k < 4; ++k) p[k] = make_float2(1e30f, 1e30f);
    }
}

// One wave per (dir, cell). Lanes = that cell's queries; ring-search the other
// cloud's grid. Target counts staged in LDS; point scans are 4-wide float4.
// Stop after ring r iff all lanes' best_d^2 <= (r*H)^2 (exact).
__global__ __launch_bounds__(256) void k_query(
        const float2* __restrict__ pc, const float2* __restrict__ ref,
        const unsigned int* __restrict__ cnt, const unsigned int* __restrict__ ovf_cnt,
        const float2* __restrict__ binned, const float2* __restrict__ ovf,
        float* __restrict__ out) {
    __shared__ unsigned int s_tcnt[NB];   // 16 KB: target-dir bin counts (clamped)

    int d    = blockIdx.y;                // query cloud
    int td   = 1 - d;                     // target cloud
    for (int i = threadIdx.x; i < NB; i += 256)
        s_tcnt[i] = min(cnt[td * NB + i], (unsigned)CAP);
    __syncthreads();

    int w    = blockIdx.x * 4 + (threadIdx.x >> 6);
    int lane = threadIdx.x & 63;
    float sum = 0.0f;

    if (w < NB) {
        int c  = w;
        int cx = c & (G - 1), cy = c >> 6;
        const float2* tbin = binned + (size_t)td * NB * CAPP;
        int nq = (int)min(cnt[d * NB + c], (unsigned)CAP);
        unsigned novf = min(ovf_cnt[td], (unsigned)OCAP);

        for (int base = 0; base < nq; base += 64) {
            bool valid = (base + lane) < nq;
            float2 q = valid ? binned[((size_t)d * NB + c) * CAPP + base + lane]
                             : make_float2(0.0f, 0.0f);
            float best = valid ? INFINITY : 0.0f;  // invalid lanes never block __all

            // Overflow targets (normally zero) — scanned unconditionally: exact.
            for (unsigned j = 0; j < novf; ++j) {
                float2 tp = ovf[td * OCAP + j];
                float ddx = q.x - tp.x, ddy = q.y - tp.y;
                best = fminf(best, fmaf(ddx, ddx, ddy * ddy));
            }

            auto scan_cell = [&](int x, int y) {
                if ((unsigned)x < G && (unsigned)y < G) {
                    int t  = y * G + x;
                    int tn = (int)s_tcnt[t];
                    const float4* tp4 = (const float4*)(tbin + (size_t)t * CAPP);
#pragma unroll 2
                    for (int j = 0; j < tn; j += 4) {
                        float4 ab = tp4[j >> 1];        // points j, j+1
                        float4 cd = tp4[(j >> 1) + 1];  // points j+2, j+3
                        float dx0 = q.x - ab.x, dy0 = q.y - ab.y;
                        float dx1 = q.x - ab.z, dy1 = q.y - ab.w;
                        float dx2 = q.x - cd.x, dy2 = q.y - cd.y;
                        float dx3 = q.x - cd.z, dy3 = q.y - cd.w;
                        float d0 = fmaf(dx0, dx0, dy0 * dy0);
                        float d1 = fmaf(dx1, dx1, dy1 * dy1);
                        float d2 = fmaf(dx2, dx2, dy2 * dy2);
                        float d3 = fmaf(dx3, dx3, dy3 * dy3);
                        best = fminf(best,
                               fminf(fminf(d0, d1), fminf(d2, d3)));
                    }
                }
            };

            for (int r = 0; r < G; ++r) {
                if (r == 0) {
                    scan_cell(cx, cy);
                } else {
                    for (int dx = -r; dx <= r; ++dx) {
                        scan_cell(cx + dx, cy - r);
                        scan_cell(cx + dx, cy + r);
                    }
                    for (int dy = -r + 1; dy <= r - 1; ++dy) {
                        scan_cell(cx - r, cy + dy);
                        scan_cell(cx + r, cy + dy);
                    }
                }
                float bound = (float)r * H;
                if (__all(best <= bound * bound)) break;
            }
            if (valid) sum += sqrtf(best);
        }
    } else if (w == NB) {
        // Overflow queries (normally none): exact brute force vs raw targets.
        unsigned n = min(ovf_cnt[d], (unsigned)OCAP);
        const float2* tgt = d ? pc : ref;
        for (unsigned i = lane; i < n; i += 64) {
            float2 q = ovf[d * OCAP + i];
            float best = INFINITY;
            for (int j = 0; j < NPTS; ++j) {
                float2 tp = tgt[j];
                float ddx = q.x - tp.x, ddy = q.y - tp.y;
                best = fminf(best, fmaf(ddx, ddx, ddy * ddy));
            }
            sum += sqrtf(best);
        }
    }

    // Wave reduction + one atomic per wave.
#pragma unroll
    for (int off = 32; off > 0; off >>= 1)
        sum += __shfl_down(sum, off, 64);
    if (lane == 0 && sum != 0.0f)
        atomicAdd(out, sum);
}

extern "C" void kernel_launch(void* const* d_in, const int* in_sizes, int n_in,
                              void* d_out, int out_size, void* d_ws, size_t ws_size,
                              hipStream_t stream) {
    const float2* pc  = (const float2*)d_in[0];  // img_render_points (128*128*2 f32)
    const float2* ref = (const float2*)d_in[1];  // ref contour (16384*2 f32)
    float* out = (float*)d_out;

    char* w = (char*)d_ws;
    unsigned int* cnt     = (unsigned int*)(w);               // [2][NB]
    unsigned int* ovf_cnt = (unsigned int*)(w + 32768);       // [2]
    float2*       binned  = (float2*)(w + 65536);             // [2][NB][CAPP]
    float2*       ovf     = (float2*)(w + 65536 +
                              (size_t)2 * NB * CAPP * sizeof(float2));

    k_zero<<<(2 * NB + 2 + 255) / 256, 256, 0, stream>>>(cnt, out);
    k_scatter<<<(2 * NPTS) / 256, 256, 0, stream>>>(pc, ref, cnt, ovf_cnt, binned, ovf);
    k_pad<<<(2 * NB + 255) / 256, 256, 0, stream>>>(cnt, binned);
    // waves: NB cells + 1 overflow wave per dir -> 1025 x-blocks of 4 waves, y = dir
    k_query<<<dim3(1025, 2), 256, 0, stream>>>(pc, ref, cnt, ovf_cnt, binned, ovf, out);
}

// Round 7
// 102.564 us; speedup vs baseline: 1.5728x; 1.1835x over previous
//
#include <hip/hip_runtime.h>
#include <math.h>

// Both clouds: 16384 x float2, coords ~ N(0,1).
#define NPTS 16384
#define G    64                 // grid is G x G
#define NB   (G * G)            // 4096 bins
#define CAP  128                // points per bin capacity (central bin E~64)
#define OCAP 2048               // overflow list capacity
#define BV   5.0f               // grid covers [-BV, BV]^2 (clamped outside)
#define H    0.15625f           // 2*BV/G cell width
#define INVH (1.0f / H)
#define SLICE 1160              // float2 slots per wave staging slice (>= 9*CAP, 16B-aligned)

// ws layout:
//   [0, 32768)     cnt[2][NB] uint
//   [32768, 32776) ovf_cnt[2] uint
//   [65536, +8 MB) binned[2][NB][CAP] float2 (cell-sorted)
//   then           ovf[2][OCAP] float2

__global__ __launch_bounds__(256) void k_zero(unsigned int* __restrict__ cnt,
                                              float* __restrict__ out) {
    int i = blockIdx.x * 256 + threadIdx.x;
    if (i < 2 * NB + 2) cnt[i] = 0u;   // cnt[2][NB] + ovf_cnt[2] contiguous
    if (i == 0) out[0] = 0.0f;
}

__global__ __launch_bounds__(256) void k_scatter(
        const float2* __restrict__ pc, const float2* __restrict__ ref,
        unsigned int* __restrict__ cnt, unsigned int* __restrict__ ovf_cnt,
        float2* __restrict__ binned, float2* __restrict__ ovf) {
    int t  = blockIdx.x * 256 + threadIdx.x;   // 0..32767
    int cl = t >> 14;                          // cloud: 0=pc, 1=ref
    int i  = t & (NPTS - 1);
    float2 p = (cl ? ref : pc)[i];
    int bx = (int)floorf((p.x + BV) * INVH); bx = min(max(bx, 0), G - 1);
    int by = (int)floorf((p.y + BV) * INVH); by = min(max(by, 0), G - 1);
    int b = cl * NB + by * G + bx;
    unsigned idx = atomicAdd(&cnt[b], 1u);
    if (idx < CAP) {
        binned[(size_t)b * CAP + idx] = p;
    } else {
        unsigned oi = atomicAdd(&ovf_cnt[cl], 1u);
        if (oi < OCAP) ovf[cl * OCAP + oi] = p;
    }
}

// One wave per (dir, cell), cell index swizzled to spread dense cells.
// Rings 0+1 (3x3) cooperatively staged into LDS, computed from LDS broadcast.
// Rings >= 2 (rare): parallel count probe + ballot, scalar scan of nonempty cells.
__global__ __launch_bounds__(256) void k_query(
        const float2* __restrict__ pc, const float2* __restrict__ ref,
        const unsigned int* __restrict__ cnt, const unsigned int* __restrict__ ovf_cnt,
        const float2* __restrict__ binned, const float2* __restrict__ ovf,
        float* __restrict__ out) {
    __shared__ float2 s_pts[4 * SLICE];   // 37120 B: per-wave staging slices
    __shared__ float  s_bsum[4];

    int d    = blockIdx.y;                // query cloud
    int td   = 1 - d;                     // target cloud
    int wave = threadIdx.x >> 6;
    int lane = threadIdx.x & 63;
    int w    = blockIdx.x * 4 + wave;
    float2* my = s_pts + wave * SLICE;
    float sum = 0.0f;

    if (w < NB) {
        int c  = (w * 65) & (NB - 1);     // bijective swizzle: spread dense cells
        int cx = c & (G - 1), cy = c >> 6;
        int nq = (int)min(cnt[d * NB + c], (unsigned)CAP);
        if (nq > 0) {
            const unsigned int* tcnt = cnt + td * NB;
            const float2* tbin = binned + (size_t)td * NB * CAP;
            unsigned novf = min(ovf_cnt[td], (unsigned)OCAP);

            // ---- cooperative staging of 3x3 neighborhood into this wave's slice
            int nt = 0;
#pragma unroll
            for (int dy = -1; dy <= 1; ++dy) {
#pragma unroll
                for (int dx = -1; dx <= 1; ++dx) {
                    int x = cx + dx, y = cy + dy;
                    if ((unsigned)x < G && (unsigned)y < G) {
                        int t  = y * G + x;
                        int tn = (int)min(tcnt[t], (unsigned)CAP);  // wave-uniform
                        for (int i = lane; i < tn; i += 64)
                            my[nt + i] = tbin[(size_t)t * CAP + i]; // coalesced
                        nt += tn;
                    }
                }
            }
            int ntr = (nt + 3) & ~3;          // sentinel-pad to multiple of 4
            if (lane < ntr - nt) my[nt + lane] = make_float2(1e30f, 1e30f);

            for (int base = 0; base < nq; base += 64) {
                bool valid = (base + lane) < nq;
                float2 q = valid ? binned[((size_t)(d * NB + c)) * CAP + base + lane]
                                 : make_float2(0.0f, 0.0f);
                float best = valid ? INFINITY : 0.0f;  // invalid lanes never block __all

                // Overflow targets (normally zero) — scanned unconditionally: exact.
                for (unsigned j = 0; j < novf; ++j) {
                    float2 tp = ovf[td * OCAP + j];
                    float ddx = q.x - tp.x, ddy = q.y - tp.y;
                    best = fminf(best, fmaf(ddx, ddx, ddy * ddy));
                }

                // ---- rings 0+1 from LDS (broadcast reads, 4 points/iter)
                const float4* p4 = (const float4*)my;
#pragma unroll 4
                for (int k = 0; k < ntr; k += 4) {
                    float4 ab = p4[k >> 1];
                    float4 cd = p4[(k >> 1) + 1];
                    float dx0 = q.x - ab.x, dy0 = q.y - ab.y;
                    float dx1 = q.x - ab.z, dy1 = q.y - ab.w;
                    float dx2 = q.x - cd.x, dy2 = q.y - cd.y;
                    float dx3 = q.x - cd.z, dy3 = q.y - cd.w;
                    float d0 = fmaf(dx0, dx0, dy0 * dy0);
                    float d1 = fmaf(dx1, dx1, dy1 * dy1);
                    float d2 = fmaf(dx2, dx2, dy2 * dy2);
                    float d3 = fmaf(dx3, dx3, dy3 * dy3);
                    best = fminf(best, fminf(fminf(d0, d1), fminf(d2, d3)));
                }

                // ---- rings >= 2: stop before ring r iff best <= ((r-1)*H)^2
                for (int r = 2; r < G; ++r) {
                    float bnd = (float)(r - 1) * H;
                    if (__all(best <= bnd * bnd)) break;
                    int ncells = 8 * r;
                    for (int k0 = 0; k0 < ncells; k0 += 64) {
                        int k = k0 + lane;
                        int t = 0, tn = 0;
                        if (k < ncells) {
                            int side = (k >= 6 * r) ? 3 : (k >= 4 * r) ? 2 :
                                       (k >= 2 * r) ? 1 : 0;
                            int i = k - side * 2 * r;
                            int x, y;
                            if      (side == 0) { y = cy - r; x = cx - r + i; }
                            else if (side == 1) { x = cx + r; y = cy - r + i; }
                            else if (side == 2) { y = cy + r; x = cx + r - i; }
                            else                { x = cx - r; y = cy + r - i; }
                            if ((unsigned)x < G && (unsigned)y < G) {
                                t  = y * G + x;
                                tn = (int)min(tcnt[t], (unsigned)CAP);
                            }
                        }
                        unsigned long long mask = __ballot(tn > 0);
                        while (mask) {
                            int src = __builtin_ctzll(mask);
                            mask &= mask - 1;
                            int tt  = __shfl(t,  src, 64);
                            int ttn = __shfl(tn, src, 64);
                            const float2* tp = tbin + (size_t)tt * CAP;
                            for (int j = 0; j < ttn; ++j) {
                                float2 pt = tp[j];   // broadcast (rare path)
                                float ddx = q.x - pt.x, ddy = q.y - pt.y;
                                best = fminf(best, fmaf(ddx, ddx, ddy * ddy));
                            }
                        }
                    }
                }
                if (valid) sum += sqrtf(best);
            }
        }
    } else if (w == NB) {
        // Overflow queries (normally none): exact brute force vs raw targets.
        unsigned n = min(ovf_cnt[d], (unsigned)OCAP);
        const float2* tgt = d ? pc : ref;
        for (unsigned i = lane; i < n; i += 64) {
            float2 q = ovf[d * OCAP + i];
            float best = INFINITY;
            for (int j = 0; j < NPTS; ++j) {
                float2 tp = tgt[j];
                float ddx = q.x - tp.x, ddy = q.y - tp.y;
                best = fminf(best, fmaf(ddx, ddx, ddy * ddy));
            }
            sum += sqrtf(best);
        }
    }

    // Wave reduce -> block reduce -> one atomic per block.
#pragma unroll
    for (int off = 32; off > 0; off >>= 1)
        sum += __shfl_down(sum, off, 64);
    if (lane == 0) s_bsum[wave] = sum;
    __syncthreads();
    if (threadIdx.x == 0) {
        float t = s_bsum[0] + s_bsum[1] + s_bsum[2] + s_bsum[3];
        if (t != 0.0f) atomicAdd(out, t);
    }
}

extern "C" void kernel_launch(void* const* d_in, const int* in_sizes, int n_in,
                              void* d_out, int out_size, void* d_ws, size_t ws_size,
                              hipStream_t stream) {
    const float2* pc  = (const float2*)d_in[0];  // img_render_points (128*128*2 f32)
    const float2* ref = (const float2*)d_in[1];  // ref contour (16384*2 f32)
    float* out = (float*)d_out;

    char* w = (char*)d_ws;
    unsigned int* cnt     = (unsigned int*)(w);               // [2][NB]
    unsigned int* ovf_cnt = (unsigned int*)(w + 32768);       // [2]
    float2*       binned  = (float2*)(w + 65536);             // [2][NB][CAP]
    float2*       ovf     = (float2*)(w + 65536 +
                              (size_t)2 * NB * CAP * sizeof(float2));

    k_zero<<<(2 * NB + 2 + 255) / 256, 256, 0, stream>>>(cnt, out);
    k_scatter<<<(2 * NPTS) / 256, 256, 0, stream>>>(pc, ref, cnt, ovf_cnt, binned, ovf);
    // NB cell-waves + 1 overflow wave per dir -> 1025 x-blocks of 4 waves, y = dir
    k_query<<<dim3(1025, 2), 256, 0, stream>>>(pc, ref, cnt, ovf_cnt, binned, ovf, out);
}

// Round 8
// 88.864 us; speedup vs baseline: 1.8152x; 1.1542x over previous
//
#include <hip/hip_runtime.h>
#include <math.h>

// Both clouds: 16384 x float2, coords ~ N(0,1).
#define NPTS 16384
#define G    64                 // grid is G x G
#define NB   (G * G)            // 4096 bins
#define CAP  128                // points per bin capacity (central bin E~64)
#define OCAP 2048               // overflow list capacity
#define BV   5.0f               // grid covers [-BV, BV]^2 (clamped outside)
#define H    0.15625f           // 2*BV/G cell width
#define INVH (1.0f / H)
#define SLICE 1160              // float2 slots per wave slice (9*CAP=1152 fits)
#define WCAP  1152              // ring-staging window size (multiple of 4)

// ws layout:
//   [0, 32768)     cnt[2][NB] uint
//   [32768, 32776) ovf_cnt[2] uint
//   [65536, +8 MB) binned[2][NB][CAP] float2 (cell-sorted)
//   then           ovf[2][OCAP] float2

__global__ __launch_bounds__(256) void k_zero(unsigned int* __restrict__ cnt,
                                              float* __restrict__ out) {
    int i = blockIdx.x * 256 + threadIdx.x;
    if (i < 2 * NB + 2) cnt[i] = 0u;   // cnt[2][NB] + ovf_cnt[2] contiguous
    if (i == 0) out[0] = 0.0f;
}

__global__ __launch_bounds__(256) void k_scatter(
        const float2* __restrict__ pc, const float2* __restrict__ ref,
        unsigned int* __restrict__ cnt, unsigned int* __restrict__ ovf_cnt,
        float2* __restrict__ binned, float2* __restrict__ ovf) {
    int t  = blockIdx.x * 256 + threadIdx.x;   // 0..32767
    int cl = t >> 14;                          // cloud: 0=pc, 1=ref
    int i  = t & (NPTS - 1);
    float2 p = (cl ? ref : pc)[i];
    int bx = (int)floorf((p.x + BV) * INVH); bx = min(max(bx, 0), G - 1);
    int by = (int)floorf((p.y + BV) * INVH); by = min(max(by, 0), G - 1);
    int b = cl * NB + by * G + bx;
    unsigned idx = atomicAdd(&cnt[b], 1u);
    if (idx < CAP) {
        binned[(size_t)b * CAP + idx] = p;
    } else {
        unsigned oi = atomicAdd(&ovf_cnt[cl], 1u);
        if (oi < OCAP) ovf[cl * OCAP + oi] = p;
    }
}

// One wave per (dir, cell), swizzled. Q=2 queries/lane (nq<=128) in ONE pass.
// 3x3 neighborhood cooperatively staged to LDS; rings>=2 staged per-ring via
// prefix-sum + windowed parallel copy, then scanned from LDS. Fully exact.
__global__ __launch_bounds__(256) void k_query(
        const float2* __restrict__ pc, const float2* __restrict__ ref,
        const unsigned int* __restrict__ cnt, const unsigned int* __restrict__ ovf_cnt,
        const float2* __restrict__ binned, const float2* __restrict__ ovf,
        float* __restrict__ out) {
    __shared__ float2 s_pts[4 * SLICE];   // 37120 B: per-wave staging slices
    __shared__ float  s_bsum[4];

    int d    = blockIdx.y;                // query cloud
    int td   = 1 - d;                     // target cloud
    int wave = threadIdx.x >> 6;
    int lane = threadIdx.x & 63;
    int w    = blockIdx.x * 4 + wave;
    float2* my = s_pts + wave * SLICE;
    float sum = 0.0f;

    if (w < NB) {
        int c  = (w * 65) & (NB - 1);     // bijective swizzle: spread dense cells
        int cx = c & (G - 1), cy = c >> 6;
        int nq = (int)min(cnt[d * NB + c], (unsigned)CAP);
        if (nq > 0) {
            const unsigned int* tcnt = cnt + td * NB;
            const float2* tbin = binned + (size_t)td * NB * CAP;
            unsigned novf = min(ovf_cnt[td], (unsigned)OCAP);

            // ---- parallel 3x3 count probe (independent loads), then copy
            int tid9[9], tn9[9], nv = 0;
#pragma unroll
            for (int dy = -1; dy <= 1; ++dy)
#pragma unroll
                for (int dx = -1; dx <= 1; ++dx) {
                    int x = cx + dx, y = cy + dy;
                    if ((unsigned)x < G && (unsigned)y < G) {
                        tid9[nv] = y * G + x;
                        tn9[nv]  = (int)min(tcnt[y * G + x], (unsigned)CAP);
                        ++nv;
                    }
                }
            int nt = 0;
            for (int v = 0; v < nv; ++v) {
                int t = tid9[v], tn = tn9[v];
                for (int i = lane; i < tn; i += 64)
                    my[nt + i] = tbin[(size_t)t * CAP + i];   // coalesced
                nt += tn;
            }
            int ntr = (nt + 3) & ~3;
            if (lane < ntr - nt) my[nt + lane] = make_float2(1e30f, 1e30f);

            // ---- load 2 queries per lane (slots always in-bounds; poison-safe)
            bool v0 = lane < nq, v1 = (64 + lane) < nq;
            const float2* qbin = binned + (size_t)(d * NB + c) * CAP;
            float2 q0 = qbin[lane];
            float2 q1 = qbin[64 + lane];
            float b0 = v0 ? INFINITY : 0.0f;   // invalid lanes never block __all
            float b1 = v1 ? INFINITY : 0.0f;

            // Overflow targets (normally zero) — scanned unconditionally: exact.
            for (unsigned j = 0; j < novf; ++j) {
                float2 tp = ovf[td * OCAP + j];
                float ax = q0.x - tp.x, ay = q0.y - tp.y;
                float bx = q1.x - tp.x, by = q1.y - tp.y;
                b0 = fminf(b0, fmaf(ax, ax, ay * ay));
                b1 = fminf(b1, fmaf(bx, bx, by * by));
            }

            // ---- scan helper: 4 points/iter from this wave's LDS slice
            auto scan_lds = [&](int n4) {
                const float4* p4 = (const float4*)my;
#pragma unroll 4
                for (int k = 0; k < n4; k += 4) {
                    float4 ab = p4[k >> 1];
                    float4 cd = p4[(k >> 1) + 1];
                    float x0 = q0.x - ab.x, y0 = q0.y - ab.y;
                    float x1 = q0.x - ab.z, y1 = q0.y - ab.w;
                    float x2 = q0.x - cd.x, y2 = q0.y - cd.y;
                    float x3 = q0.x - cd.z, y3 = q0.y - cd.w;
                    float d0 = fmaf(x0, x0, y0 * y0);
                    float d1 = fmaf(x1, x1, y1 * y1);
                    float d2 = fmaf(x2, x2, y2 * y2);
                    float d3 = fmaf(x3, x3, y3 * y3);
                    b0 = fminf(b0, fminf(fminf(d0, d1), fminf(d2, d3)));
                    float u0 = q1.x - ab.x, w0 = q1.y - ab.y;
                    float u1 = q1.x - ab.z, w1 = q1.y - ab.w;
                    float u2 = q1.x - cd.x, w2 = q1.y - cd.y;
                    float u3 = q1.x - cd.z, w3 = q1.y - cd.w;
                    float e0 = fmaf(u0, u0, w0 * w0);
                    float e1 = fmaf(u1, u1, w1 * w1);
                    float e2 = fmaf(u2, u2, w2 * w2);
                    float e3 = fmaf(u3, u3, w3 * w3);
                    b1 = fminf(b1, fminf(fminf(e0, e1), fminf(e2, e3)));
                }
            };

            scan_lds(ntr);   // rings 0+1

            // ---- rings >= 2: stop before ring r iff all best <= ((r-1)*H)^2
            for (int r = 2; r < G; ++r) {
                float bnd = (float)(r - 1) * H;
                if (__all(fmaxf(b0, b1) <= bnd * bnd)) break;
                int ncells = 8 * r;
                for (int k0 = 0; k0 < ncells; k0 += 64) {
                    int k = k0 + lane;
                    int t = 0, tn = 0;
                    if (k < ncells) {
                        int side = (k >= 6 * r) ? 3 : (k >= 4 * r) ? 2 :
                                   (k >= 2 * r) ? 1 : 0;
                        int i = k - side * 2 * r;
                        int x, y;
                        if      (side == 0) { y = cy - r; x = cx - r + i; }
                        else if (side == 1) { x = cx + r; y = cy - r + i; }
                        else if (side == 2) { y = cy + r; x = cx + r - i; }
                        else                { x = cx - r; y = cy + r - i; }
                        if ((unsigned)x < G && (unsigned)y < G) {
                            t  = y * G + x;
                            tn = (int)min(tcnt[t], (unsigned)CAP);
                        }
                    }
                    // exclusive prefix of tn across the wave
                    int incl = tn;
#pragma unroll
                    for (int s = 1; s < 64; s <<= 1) {
                        int o = __shfl_up(incl, s, 64);
                        if (lane >= s) incl += o;
                    }
                    int off   = incl - tn;
                    int total = __shfl(incl, 63, 64);
                    // windowed parallel stage + LDS scan (exact for any total)
                    for (int start = 0; start < total; start += WCAP) {
                        int wend = min(total, start + WCAP);
                        int wn   = wend - start;
                        for (int j = 0; j < tn; ++j) {
                            int g = off + j;
                            if (g >= start && g < wend)
                                my[g - start] = tbin[(size_t)t * CAP + j];
                        }
                        int wnr = (wn + 3) & ~3;
                        if (lane < wnr - wn) my[wn + lane] = make_float2(1e30f, 1e30f);
                        scan_lds(wnr);
                    }
                }
            }
            sum = (v0 ? sqrtf(b0) : 0.0f) + (v1 ? sqrtf(b1) : 0.0f);
        }
    } else if (w == NB) {
        // Overflow queries (normally none): exact brute force vs raw targets.
        unsigned n = min(ovf_cnt[d], (unsigned)OCAP);
        const float2* tgt = d ? pc : ref;
        for (unsigned i = lane; i < n; i += 64) {
            float2 q = ovf[d * OCAP + i];
            float best = INFINITY;
            for (int j = 0; j < NPTS; ++j) {
                float2 tp = tgt[j];
                float ddx = q.x - tp.x, ddy = q.y - tp.y;
                best = fminf(best, fmaf(ddx, ddx, ddy * ddy));
            }
            sum += sqrtf(best);
        }
    }

    // Wave reduce -> block reduce -> one atomic per block.
#pragma unroll
    for (int off = 32; off > 0; off >>= 1)
        sum += __shfl_down(sum, off, 64);
    if (lane == 0) s_bsum[wave] = sum;
    __syncthreads();
    if (threadIdx.x == 0) {
        float t = s_bsum[0] + s_bsum[1] + s_bsum[2] + s_bsum[3];
        if (t != 0.0f) atomicAdd(out, t);
    }
}

extern "C" void kernel_launch(void* const* d_in, const int* in_sizes, int n_in,
                              void* d_out, int out_size, void* d_ws, size_t ws_size,
                              hipStream_t stream) {
    const float2* pc  = (const float2*)d_in[0];  // img_render_points (128*128*2 f32)
    const float2* ref = (const float2*)d_in[1];  // ref contour (16384*2 f32)
    float* out = (float*)d_out;

    char* w = (char*)d_ws;
    unsigned int* cnt     = (unsigned int*)(w);               // [2][NB]
    unsigned int* ovf_cnt = (unsigned int*)(w + 32768);       // [2]
    float2*       binned  = (float2*)(w + 65536);             // [2][NB][CAP]
    float2*       ovf     = (float2*)(w + 65536 +
                              (size_t)2 * NB * CAP * sizeof(float2));

    k_zero<<<(2 * NB + 2 + 255) / 256, 256, 0, stream>>>(cnt, out);
    k_scatter<<<(2 * NPTS) / 256, 256, 0, stream>>>(pc, ref, cnt, ovf_cnt, binned, ovf);
    // NB cell-waves + 1 overflow wave per dir -> 1025 x-blocks of 4 waves, y = dir
    k_query<<<dim3(1025, 2), 256, 0, stream>>>(pc, ref, cnt, ovf_cnt, binned, ovf, out);
}